// Round 5
// baseline (131.261 us; speedup 1.0000x reference)
//
#include <hip/hip_runtime.h>
#include <stdint.h>

// Problem constants
#define CH 8      // heads
#define CDH 64    // dim head
#define CB 2      // batch
#define CN 2048   // seq
#define CD 512    // model dim

typedef float f32x4 __attribute__((ext_vector_type(4)));
typedef __bf16 bf16x8 __attribute__((ext_vector_type(8)));
typedef unsigned short u16;

#define MFMA(a, b, c) __builtin_amdgcn_mfma_f32_16x16x32_bf16((a), (b), (c), 0, 0, 0)
#define GLOAD16(g, l)                                                              \
  __builtin_amdgcn_global_load_lds((const __attribute__((address_space(1))) void*)(g), \
                                   (__attribute__((address_space(3))) void*)(l), 16, 0, 0)

__device__ __forceinline__ u16 f2bf(float f) {
  union { float f; unsigned u; } c; c.f = f;
  return (u16)((c.u + 0x7FFFu + ((c.u >> 16) & 1u)) >> 16);
}
__device__ __forceinline__ u16 f2bf_hw(float f) {
  union { __bf16 h; u16 u; } c; c.h = (__bf16)f;
  return c.u;
}
__device__ __forceinline__ float bf2f(u16 h) {
  union { unsigned u; float f; } c; c.u = ((unsigned)h) << 16;
  return c.f;
}

// ---------------------------------------------------------------------------
// K0: LayerNorm over D=512 for q,k,v -> xln bf16 [3*4096][512]
// ---------------------------------------------------------------------------
__global__ __launch_bounds__(256) void ln_kernel(const float* __restrict__ q,
                                                 const float* __restrict__ k,
                                                 const float* __restrict__ v,
                                                 const float* __restrict__ g,
                                                 const float* __restrict__ bb,
                                                 u16* __restrict__ xln) {
  int row = blockIdx.x;                 // 0..12287
  int t = row >> 12;                    // /4096
  int rr = row & 4095;
  const float* src = (t == 0 ? q : (t == 1 ? k : v)) + (size_t)rr * CD;
  int tid = threadIdx.x;
  float x0 = src[tid], x1 = src[tid + 256];
  float s = x0 + x1, s2 = x0 * x0 + x1 * x1;
#pragma unroll
  for (int m = 1; m < 64; m <<= 1) { s += __shfl_xor(s, m); s2 += __shfl_xor(s2, m); }
  __shared__ float red[8];
  int w = tid >> 6;
  if ((tid & 63) == 0) { red[w] = s; red[4 + w] = s2; }
  __syncthreads();
  s = red[0] + red[1] + red[2] + red[3];
  s2 = red[4] + red[5] + red[6] + red[7];
  float mean = s * (1.f / 512.f);
  float var = s2 * (1.f / 512.f) - mean * mean;
  float rstd = rsqrtf(var + 1e-5f);
  u16* dst = xln + (size_t)row * CD;
  dst[tid]       = f2bf((x0 - mean) * rstd * g[tid] + bb[tid]);
  dst[tid + 256] = f2bf((x1 - mean) * rstd * g[tid + 256] + bb[tid + 256]);
}

// ---------------------------------------------------------------------------
// K0w: convert W_in, W_out to bf16
// ---------------------------------------------------------------------------
__global__ __launch_bounds__(256) void convw_kernel(const float* __restrict__ wi_f,
                                                    const float* __restrict__ wo_f,
                                                    u16* __restrict__ wi,
                                                    u16* __restrict__ wo) {
  int i = blockIdx.x * 256 + threadIdx.x;   // < 262144
  wi[i] = f2bf(wi_f[i]);
  wo[i] = f2bf(wo_f[i]);
}

// ---------------------------------------------------------------------------
// Generic C = A * Bt^T bf16 MFMA GEMM, K=512, BM=BN=128, BK=64, double-buffered
// ---------------------------------------------------------------------------
template <int OUT_BF16, int ADD_BIAS>
__global__ __launch_bounds__(256) void gemm_bt(const u16* __restrict__ A,
                                               const u16* __restrict__ Bt,
                                               void* __restrict__ Cout,
                                               const float* __restrict__ bias) {
  __shared__ u16 Al[2][128 * 64];
  __shared__ u16 Bl[2][128 * 64];
  int tm = blockIdx.x * 128, tn = blockIdx.y * 128;
  int tid = threadIdx.x;
  int w = tid >> 6, l = tid & 63;
  int wr = w >> 1, wc = w & 1;

  f32x4 zz = {0.f, 0.f, 0.f, 0.f};
  f32x4 acc[4][4];
#pragma unroll
  for (int mi = 0; mi < 4; mi++)
#pragma unroll
    for (int ni = 0; ni < 4; ni++) acc[mi][ni] = zz;

  int rowA = 8 * w + (l >> 3);
  int sl = l & 7;

#pragma unroll
  for (int i = 0; i < 4; i++) {
    int rl = rowA + 32 * i;
    int sp = sl ^ (rl & 7);
    GLOAD16(A + (size_t)(tm + rl) * CD + sp * 8, (char*)Al[0] + w * 1024 + i * 4096);
    GLOAD16(Bt + (size_t)(tn + rl) * CD + sp * 8, (char*)Bl[0] + w * 1024 + i * 4096);
  }
  __syncthreads();

  int cur = 0;
  for (int kt = 0; kt < 8; ++kt) {
    if (kt + 1 < 8) {
      int nxt = cur ^ 1;
#pragma unroll
      for (int i = 0; i < 4; i++) {
        int rl = rowA + 32 * i;
        int sp = sl ^ (rl & 7);
        GLOAD16(A + (size_t)(tm + rl) * CD + (kt + 1) * 64 + sp * 8,
                (char*)Al[nxt] + w * 1024 + i * 4096);
        GLOAD16(Bt + (size_t)(tn + rl) * CD + (kt + 1) * 64 + sp * 8,
                (char*)Bl[nxt] + w * 1024 + i * 4096);
      }
    }
    const u16* Ac = Al[cur];
    const u16* Bc = Bl[cur];
#pragma unroll
    for (int kk = 0; kk < 2; kk++) {
      bf16x8 af[4], bfr[4];
#pragma unroll
      for (int mi = 0; mi < 4; mi++) {
        int row = wr * 64 + mi * 16 + (l & 15);
        int slot = ((l >> 4) + 4 * kk) ^ (row & 7);
        af[mi] = *(const bf16x8*)&Ac[row * 64 + slot * 8];
      }
#pragma unroll
      for (int ni = 0; ni < 4; ni++) {
        int row = wc * 64 + ni * 16 + (l & 15);
        int slot = ((l >> 4) + 4 * kk) ^ (row & 7);
        bfr[ni] = *(const bf16x8*)&Bc[row * 64 + slot * 8];
      }
#pragma unroll
      for (int mi = 0; mi < 4; mi++)
#pragma unroll
        for (int ni = 0; ni < 4; ni++)
          acc[mi][ni] = MFMA(af[mi], bfr[ni], acc[mi][ni]);
    }
    if (kt + 1 < 8) {
      __syncthreads();
      cur ^= 1;
    }
  }
#pragma unroll
  for (int mi = 0; mi < 4; mi++)
#pragma unroll
    for (int ni = 0; ni < 4; ni++) {
      int col = tn + wc * 64 + ni * 16 + (l & 15);
      float bv = ADD_BIAS ? bias[col] : 0.f;
#pragma unroll
      for (int rg = 0; rg < 4; rg++) {
        int rowg = tm + wr * 64 + mi * 16 + (l >> 4) * 4 + rg;
        float vout = acc[mi][ni][rg] + bv;
        if (OUT_BF16)
          ((u16*)Cout)[(size_t)rowg * CD + col] = f2bf(vout);
        else
          ((float*)Cout)[(size_t)rowg * CD + col] = vout;
      }
    }
}

// ---------------------------------------------------------------------------
// K1b: transpose fv + rank-1 partial
// ---------------------------------------------------------------------------
__global__ __launch_bounds__(256) void transpose_v(const u16* __restrict__ F2,
                                                   const float* __restrict__ mk,
                                                   u16* __restrict__ fvT,
                                                   float* __restrict__ rpart) {
  int bid = blockIdx.x;
  int nt = bid & 31, b = (bid >> 5) & 1, h = bid >> 6;
  __shared__ u16 T[64 * 72];
  int tid = threadIdx.x;
  int n = tid >> 2;
#pragma unroll
  for (int p = 0; p < 2; p++) {
    int c = (tid & 3) + 4 * p;
    bf16x8 vv = *(const bf16x8*)&F2[((size_t)(b * CN + nt * 64 + n) * CD) + h * 64 + c * 8];
    *(bf16x8*)&T[n * 72 + c * 8] = vv;
  }
  __syncthreads();
  int d = tid >> 2;
#pragma unroll
  for (int p = 0; p < 2; p++) {
    int c = (tid & 3) + 4 * p;
    u16 tmp[8];
#pragma unroll
    for (int j = 0; j < 8; j++) tmp[j] = T[(c * 8 + j) * 72 + d];
    *(bf16x8*)&fvT[(((size_t)(h * 2 + b) * 64 + d) * CN) + nt * 64 + c * 8] =
        *(bf16x8*)tmp;
  }
  {
    int d2 = tid & 63, sub = tid >> 6;
    const float* mkp = mk + ((size_t)(h * 2 + b)) * CN + nt * 64;
    float s = 0.f;
#pragma unroll
    for (int i = 0; i < 16; i++) {
      int n2 = sub * 16 + i;
      s += mkp[n2] * bf2f(T[n2 * 72 + d2]);
    }
    __shared__ float rred[4][64];
    rred[sub][d2] = s;
    __syncthreads();
    if (sub == 0)
      rpart[(((size_t)(h * 2 + b)) * 32 + nt) * 64 + d2] =
          rred[0][d2] + rred[1][d2] + rred[2][d2] + rred[3][d2];
  }
}

// ---------------------------------------------------------------------------
// K1c: per-(h,b,n) stats
// ---------------------------------------------------------------------------
__global__ __launch_bounds__(256) void stats_kernel(const u16* __restrict__ F,
                                                    float* __restrict__ iqn,
                                                    float* __restrict__ mq,
                                                    float* __restrict__ ikn,
                                                    float* __restrict__ mk) {
  unsigned idx = blockIdx.x * 256 + threadIdx.x;
  int h = idx & 7;
  int n = (idx >> 3) & 2047;
  int b = (idx >> 14) & 1;
  int t = idx >> 15;
  const u16* p = F + ((size_t)(t * 4096 + b * CN + n)) * CD + h * 64;
  float s1 = 0.f, s2 = 0.f;
  const uint4* p4 = (const uint4*)p;
#pragma unroll
  for (int j = 0; j < 8; j++) {
    uint4 u = p4[j];
    unsigned arr[4] = {u.x, u.y, u.z, u.w};
#pragma unroll
    for (int e = 0; e < 4; e++) {
      float lo = bf2f((u16)(arr[e] & 0xFFFF));
      float hi = bf2f((u16)(arr[e] >> 16));
      s1 += lo + hi;
      s2 += lo * lo + hi * hi;
    }
  }
  float inv = 1.f / sqrtf(s2);
  float mean = s1 * (1.f / 64.f);
  size_t o = ((size_t)h * 2 + b) * CN + n;
  if (t == 0) { iqn[o] = inv; mq[o] = mean; }
  else        { ikn[o] = inv; mk[o] = mean; }
}

// ---------------------------------------------------------------------------
// K2a: partial sums of fq,fk over rows -> qgp/kgp [32ch][8h][64]
// ---------------------------------------------------------------------------
__global__ __launch_bounds__(256) void gsum_kernel(const u16* __restrict__ F0,
                                                   const u16* __restrict__ F1,
                                                   float* __restrict__ qgp,
                                                   float* __restrict__ kgp) {
  int h = blockIdx.x & 7, ch = blockIdx.x >> 3;
  int tid = threadIdx.x;
  int r0 = tid >> 3;
  int dc = (tid & 7) * 8;
  float aq[8], ak[8];
#pragma unroll
  for (int j = 0; j < 8; j++) { aq[j] = 0.f; ak[j] = 0.f; }
#pragma unroll
  for (int i = 0; i < 4; i++) {
    int row = ch * 128 + i * 32 + r0;
    bf16x8 vq = *(const bf16x8*)&F0[(size_t)row * CD + h * 64 + dc];
    bf16x8 vk = *(const bf16x8*)&F1[(size_t)row * CD + h * 64 + dc];
#pragma unroll
    for (int j = 0; j < 8; j++) { aq[j] += (float)vq[j]; ak[j] += (float)vk[j]; }
  }
  __shared__ float red[2][32][64];
#pragma unroll
  for (int j = 0; j < 8; j++) { red[0][r0][dc + j] = aq[j]; red[1][r0][dc + j] = ak[j]; }
  __syncthreads();
  if (tid < 64) {
    float sq = 0.f, sk = 0.f;
#pragma unroll
    for (int rr = 0; rr < 32; rr++) { sq += red[0][rr][tid]; sk += red[1][rr][tid]; }
    qgp[(ch * 8 + h) * 64 + tid] = sq;
    kgp[(ch * 8 + h) * 64 + tid] = sk;
  }
}

// ---------------------------------------------------------------------------
// K2f: finalize reductions + per-head blend MLP (merged), 1 block x 1024 thr
// ---------------------------------------------------------------------------
__global__ __launch_bounds__(1024) void finalize_mlp_kernel(
    const float* __restrict__ rpart, const float* __restrict__ qgp,
    const float* __restrict__ kgp, const float* __restrict__ w1,
    const float* __restrict__ b1, const float* __restrict__ lng,
    const float* __restrict__ lnb, const float* __restrict__ w2,
    const float* __restrict__ b2, float* __restrict__ rv,
    float* __restrict__ hp) {
  int o = threadIdx.x;
  int hb = o >> 6, d = o & 63;
  float s = 0.f;
#pragma unroll
  for (int nt = 0; nt < 32; nt++) s += rpart[((size_t)hb * 32 + nt) * 64 + d];
  rv[o] = s;
  __shared__ float qg[512], kg[512];
  if (o < 512) {
    int h = o >> 6, dd = o & 63;
    float s1 = 0.f, s2 = 0.f;
#pragma unroll
    for (int c = 0; c < 32; c++) {
      s1 += qgp[(c * 8 + h) * 64 + dd];
      s2 += kgp[(c * 8 + h) * 64 + dd];
    }
    qg[o] = s1 * (1.f / 4096.f);
    kg[o] = s2 * (1.f / 4096.f);
  }
  __syncthreads();
  if (o < 512) {
    int h = o >> 6, oo = o & 63;
    float acc = b1[oo];
#pragma unroll 8
    for (int i = 0; i < 64; i++)
      acc += qg[h * 64 + i] * w1[oo * 128 + i] + kg[h * 64 + i] * w1[oo * 128 + 64 + i];
    float s1 = acc, s2 = acc * acc;
#pragma unroll
    for (int m = 1; m < 64; m <<= 1) { s1 += __shfl_xor(s1, m); s2 += __shfl_xor(s2, m); }
    float mean = s1 * (1.f / 64.f);
    float var = s2 * (1.f / 64.f) - mean * mean;
    float y = (acc - mean) * rsqrtf(var + 1e-5f) * lng[oo] + lnb[oo];
    float hid = fmaxf(y, 0.f);
    float t = hid * w2[oo];
#pragma unroll
    for (int m = 1; m < 64; m <<= 1) t += __shfl_xor(t, m);
    float wv = 1.f / (1.f + expf(-(t + b2[0])));
    if (oo == 0) {
      hp[h * 4 + 0] = 1.f - wv;
      hp[h * 4 + 1] = wv * (1.f / 64.f);
      hp[h * 4 + 2] = wv;
    }
  }
}

// ---------------------------------------------------------------------------
// K3: streaming blended attention. XCD swizzle + stage-first order.
// K staged in LDS (dbuf, shared by 4 waves); V loaded straight to REGISTERS
// (L2-resident thanks to swizzle; per-wave fragments, issued one iter ahead,
// drained by the per-iter barrier's implicit vmcnt(0)). ikn prefetched 1 iter
// ahead. Manual unroll-by-2 so all buffer/reg-set indices are compile-time.
// ---------------------------------------------------------------------------
__global__ __launch_bounds__(256) void attn_kernel(const u16* __restrict__ F0,
                                                   const u16* __restrict__ F1,
                                                   const u16* __restrict__ fvT,
                                                   const float* __restrict__ iqn,
                                                   const float* __restrict__ mq_g,
                                                   const float* __restrict__ ikn,
                                                   const float* __restrict__ hp,
                                                   const float* __restrict__ rv,
                                                   u16* __restrict__ A2) {
  // XCD swizzle (bijective, 512 = 8*64): each XCD owns 2 full (h,b) panels.
  int bid = (blockIdx.x & 7) * 64 + (blockIdx.x >> 3);
  int qt = bid & 31, b = (bid >> 5) & 1, h = bid >> 6;
  int tid = threadIdx.x, w = tid >> 6, l = tid & 63;
  float alpha = hp[h * 4 + 0], beta = hp[h * 4 + 1], gamma = hp[h * 4 + 2];

  __shared__ u16 Kl[2][64 * 64];   // K tiles (rows m, swizzled slots)
  __shared__ u16 Pl[64 * 72];      // P tile (wave-private rows)

  int qbase = qt * 64;
  int nloc = w * 16 + (l & 15);
  const u16* qp = F0 + ((size_t)(b * CN + qbase + nloc)) * CD + h * 64 + (l >> 4) * 8;
  bf16x8 aq0 = *(const bf16x8*)qp;
  bf16x8 aq1 = *(const bf16x8*)(qp + 32);

  const float* iqn_hb = iqn + ((size_t)h * 2 + b) * CN;
  const float* mq_hb = mq_g + ((size_t)h * 2 + b) * CN;
  const float* ikn_hb = ikn + ((size_t)h * 2 + b) * CN;
  float aqn[4], mqg[4];
#pragma unroll
  for (int rg = 0; rg < 4; rg++) {
    int nr = qbase + w * 16 + (l >> 4) * 4 + rg;
    aqn[rg] = alpha * iqn_hb[nr];
    mqg[rg] = gamma * mq_hb[nr];
  }

  f32x4 zz = {0.f, 0.f, 0.f, 0.f};
  f32x4 oacc[4];
#pragma unroll
  for (int db = 0; db < 4; db++) oacc[db] = zz;

  const u16* Kg = F1 + (size_t)b * CN * CD + h * 64;
  const u16* Vg = fvT + ((size_t)h * 2 + b) * 64 * CN;

  int rls = 8 * w + (l >> 3);
  int sls = l & 7;

  bf16x8 vA[8], vB[8];     // V fragment register sets (ping-pong)
  float ikA[4], ikB[4];    // per-tile inv-k-norm prefetch

  auto LOADV = [&](bf16x8 (&vf)[8], int t) {
    int mbase = t * 64;
#pragma unroll
    for (int db = 0; db < 4; db++)
#pragma unroll
      for (int c = 0; c < 2; c++)
        vf[db * 2 + c] = *(const bf16x8*)&Vg[(size_t)(db * 16 + (l & 15)) * CN +
                                             mbase + ((l >> 4) + 4 * c) * 8];
  };
  auto LOADIK = [&](float (&ik)[4], int t) {
    int mbase = t * 64;
#pragma unroll
    for (int mb = 0; mb < 4; mb++) ik[mb] = ikn_hb[mbase + mb * 16 + (l & 15)];
  };
  auto STAGEK = [&](int t, u16* kbuf) {
    int mb2 = t * 64;
#pragma unroll
    for (int i = 0; i < 2; i++) {
      int row = rls + 32 * i;
      int sp = sls ^ (row & 7);
      GLOAD16(Kg + (size_t)(mb2 + row) * CD + sp * 8,
              (char*)kbuf + w * 1024 + i * 4096);
    }
  };
  auto QKP = [&](const u16* Kc, const float (&ik)[4]) {
#pragma unroll
    for (int mb = 0; mb < 4; mb++) {
      int rowk = mb * 16 + (l & 15);
      int c0 = (l >> 4) ^ (rowk & 7);
      int c1 = ((l >> 4) + 4) ^ (rowk & 7);
      bf16x8 bk0 = *(const bf16x8*)&Kc[rowk * 64 + c0 * 8];
      bf16x8 bk1 = *(const bf16x8*)&Kc[rowk * 64 + c1 * 8];
      f32x4 dacc = zz;
      dacc = MFMA(aq0, bk0, dacc);
      dacc = MFMA(aq1, bk1, dacc);
#pragma unroll
      for (int rg = 0; rg < 4; rg++) {
        float pv = dacc[rg] * (aqn[rg] * ik[mb] + beta);
        Pl[(w * 16 + (l >> 4) * 4 + rg) * 72 + mb * 16 + (l & 15)] = f2bf_hw(pv);
      }
    }
  };
  auto PV = [&](const bf16x8 (&vf)[8]) {
#pragma unroll
    for (int c = 0; c < 2; c++) {
      bf16x8 ap = *(const bf16x8*)&Pl[(w * 16 + (l & 15)) * 72 + (l >> 4) * 8 + c * 32];
#pragma unroll
      for (int db = 0; db < 4; db++)
        oacc[db] = MFMA(ap, vf[db * 2 + c], oacc[db]);
    }
  };

  // prologue: tile 0 resources
  LOADV(vA, 0);
  LOADIK(ikA, 0);
  STAGEK(0, Kl[0]);
  __syncthreads();   // implicit vmcnt(0): K(0) in LDS, vA/ikA in regs

  for (int t = 0; t < 32; t += 2) {
    // even tile t: compute from Kl[0]/vA/ikA; prefetch t+1 into Kl[1]/vB/ikB
    LOADV(vB, t + 1);
    LOADIK(ikB, t + 1);
    STAGEK(t + 1, Kl[1]);
    QKP(Kl[0], ikA);
    PV(vA);
    __syncthreads();   // t+1 resources resident; all waves done with Kl[0]

    // odd tile t+1: compute from Kl[1]/vB/ikB; prefetch t+2 into Kl[0]/vA/ikA
    if (t + 2 < 32) {
      LOADV(vA, t + 2);
      LOADIK(ikA, t + 2);
      STAGEK(t + 2, Kl[0]);
    }
    QKP(Kl[1], ikB);
    PV(vB);
    __syncthreads();
  }

  // epilogue: rank-1 covariance correction + bf16 store
  const float* r_hb = rv + ((size_t)h * 2 + b) * 64;
#pragma unroll
  for (int db = 0; db < 4; db++) {
    int dcol = db * 16 + (l & 15);
    float rd = r_hb[dcol];
#pragma unroll
    for (int rg = 0; rg < 4; rg++) {
      int nr = qbase + w * 16 + (l >> 4) * 4 + rg;
      float v = oacc[db][rg] - mqg[rg] * rd;
      A2[((size_t)(b * CN + nr)) * CD + h * 64 + dcol] = f2bf(v);
    }
  }
}

// ---------------------------------------------------------------------------
extern "C" void kernel_launch(void* const* d_in, const int* in_sizes, int n_in,
                              void* d_out, int out_size, void* d_ws, size_t ws_size,
                              hipStream_t stream) {
  const float* q = (const float*)d_in[0];
  const float* k = (const float*)d_in[1];
  const float* v = (const float*)d_in[2];
  const float* ln_g = (const float*)d_in[3];
  const float* ln_b = (const float*)d_in[4];
  const float* W_in = (const float*)d_in[5];
  const float* wp_w1 = (const float*)d_in[6];
  const float* wp_b1 = (const float*)d_in[7];
  const float* wp_lng = (const float*)d_in[8];
  const float* wp_lnb = (const float*)d_in[9];
  const float* wp_w2 = (const float*)d_in[10];
  const float* wp_b2 = (const float*)d_in[11];
  const float* W_out = (const float*)d_in[12];
  const float* b_out = (const float*)d_in[13];

  char* ws = (char*)d_ws;
  u16* xln = (u16*)(ws + 0);              // 12,582,912 B
  u16* F = (u16*)(ws + 12582912);         // 12,582,912 B  [3][B][N][512]
  u16* Wi = (u16*)(ws + 25165824);        // 524,288 B
  u16* Wo = (u16*)(ws + 25690112);        // 524,288 B
  u16* fvT = (u16*)(ws + 26214400);       // 4,194,304 B   [H][B][64][2048]
  u16* A2 = (u16*)(ws + 30408704);        // 4,194,304 B   [B][N][512]
  float* iqn = (float*)(ws + 34603008);   // 131,072 B each
  float* mq = (float*)(ws + 34734080);
  float* ikn = (float*)(ws + 34865152);
  float* mk = (float*)(ws + 34996224);
  float* qgp = (float*)(ws + 35127296);   // 65,536 B
  float* kgp = (float*)(ws + 35192832);   // 65,536 B
  float* hp = (float*)(ws + 35258368);    // 128 B
  float* rv = (float*)(ws + 35258496);    // 4,096 B
  float* rpart = (float*)(ws + 35262592); // 131,072 B

  u16* F0 = F;
  u16* F1 = F + 2097152;
  u16* F2 = F + 4194304;

  ln_kernel<<<12288, 256, 0, stream>>>(q, k, v, ln_g, ln_b, xln);
  convw_kernel<<<1024, 256, 0, stream>>>(W_in, W_out, Wi, Wo);
  gemm_bt<1, 0><<<dim3(96, 4), 256, 0, stream>>>(xln, Wi, (void*)F, nullptr);
  stats_kernel<<<256, 256, 0, stream>>>(F, iqn, mq, ikn, mk);
  transpose_v<<<512, 256, 0, stream>>>(F2, mk, fvT, rpart);
  gsum_kernel<<<256, 256, 0, stream>>>(F0, F1, qgp, kgp);
  finalize_mlp_kernel<<<1, 1024, 0, stream>>>(rpart, qgp, kgp, wp_w1, wp_b1,
                                              wp_lng, wp_lnb, wp_w2, wp_b2, rv, hp);
  attn_kernel<<<512, 256, 0, stream>>>(F0, F1, fvT, iqn, mq, ikn, hp, rv, A2);
  gemm_bt<0, 1><<<dim3(32, 4), 256, 0, stream>>>(A2, Wo, d_out, b_out);
}

// Round 6
// 97.448 us; speedup vs baseline: 1.3470x; 1.3470x over previous
//
#include <hip/hip_runtime.h>
#include <stdint.h>

// Problem constants
#define CH 8      // heads
#define CDH 64    // dim head
#define CB 2      // batch
#define CN 2048   // seq
#define CD 512    // model dim

typedef float f32x4 __attribute__((ext_vector_type(4)));
typedef __bf16 bf16x8 __attribute__((ext_vector_type(8)));
typedef unsigned short u16;

#define MFMA(a, b, c) __builtin_amdgcn_mfma_f32_16x16x32_bf16((a), (b), (c), 0, 0, 0)
#define GLOAD16(g, l)                                                              \
  __builtin_amdgcn_global_load_lds((const __attribute__((address_space(1))) void*)(g), \
                                   (__attribute__((address_space(3))) void*)(l), 16, 0, 0)

__device__ __forceinline__ u16 f2bf(float f) {
  union { float f; unsigned u; } c; c.f = f;
  return (u16)((c.u + 0x7FFFu + ((c.u >> 16) & 1u)) >> 16);
}
__device__ __forceinline__ u16 f2bf_hw(float f) {
  union { __bf16 h; u16 u; } c; c.h = (__bf16)f;
  return c.u;
}
__device__ __forceinline__ float bf2f(u16 h) {
  union { unsigned u; float f; } c; c.u = ((unsigned)h) << 16;
  return c.f;
}

// ---------------------------------------------------------------------------
// K0: LayerNorm over D=512 for q,k,v -> xln bf16 [3*4096][512]
// ---------------------------------------------------------------------------
__global__ __launch_bounds__(256) void ln_kernel(const float* __restrict__ q,
                                                 const float* __restrict__ k,
                                                 const float* __restrict__ v,
                                                 const float* __restrict__ g,
                                                 const float* __restrict__ bb,
                                                 u16* __restrict__ xln) {
  int row = blockIdx.x;                 // 0..12287
  int t = row >> 12;                    // /4096
  int rr = row & 4095;
  const float* src = (t == 0 ? q : (t == 1 ? k : v)) + (size_t)rr * CD;
  int tid = threadIdx.x;
  float x0 = src[tid], x1 = src[tid + 256];
  float s = x0 + x1, s2 = x0 * x0 + x1 * x1;
#pragma unroll
  for (int m = 1; m < 64; m <<= 1) { s += __shfl_xor(s, m); s2 += __shfl_xor(s2, m); }
  __shared__ float red[8];
  int w = tid >> 6;
  if ((tid & 63) == 0) { red[w] = s; red[4 + w] = s2; }
  __syncthreads();
  s = red[0] + red[1] + red[2] + red[3];
  s2 = red[4] + red[5] + red[6] + red[7];
  float mean = s * (1.f / 512.f);
  float var = s2 * (1.f / 512.f) - mean * mean;
  float rstd = rsqrtf(var + 1e-5f);
  u16* dst = xln + (size_t)row * CD;
  dst[tid]       = f2bf((x0 - mean) * rstd * g[tid] + bb[tid]);
  dst[tid + 256] = f2bf((x1 - mean) * rstd * g[tid + 256] + bb[tid + 256]);
}

// ---------------------------------------------------------------------------
// K0w: convert W_in, W_out to bf16
// ---------------------------------------------------------------------------
__global__ __launch_bounds__(256) void convw_kernel(const float* __restrict__ wi_f,
                                                    const float* __restrict__ wo_f,
                                                    u16* __restrict__ wi,
                                                    u16* __restrict__ wo) {
  int i = blockIdx.x * 256 + threadIdx.x;   // < 262144
  wi[i] = f2bf(wi_f[i]);
  wo[i] = f2bf(wo_f[i]);
}

// ---------------------------------------------------------------------------
// Generic C = A * Bt^T bf16 MFMA GEMM, K=512, BM=BN=128, BK=64, double-buffered
// ---------------------------------------------------------------------------
template <int OUT_BF16, int ADD_BIAS>
__global__ __launch_bounds__(256) void gemm_bt(const u16* __restrict__ A,
                                               const u16* __restrict__ Bt,
                                               void* __restrict__ Cout,
                                               const float* __restrict__ bias) {
  __shared__ u16 Al[2][128 * 64];
  __shared__ u16 Bl[2][128 * 64];
  int tm = blockIdx.x * 128, tn = blockIdx.y * 128;
  int tid = threadIdx.x;
  int w = tid >> 6, l = tid & 63;
  int wr = w >> 1, wc = w & 1;

  f32x4 zz = {0.f, 0.f, 0.f, 0.f};
  f32x4 acc[4][4];
#pragma unroll
  for (int mi = 0; mi < 4; mi++)
#pragma unroll
    for (int ni = 0; ni < 4; ni++) acc[mi][ni] = zz;

  int rowA = 8 * w + (l >> 3);
  int sl = l & 7;

#pragma unroll
  for (int i = 0; i < 4; i++) {
    int rl = rowA + 32 * i;
    int sp = sl ^ (rl & 7);
    GLOAD16(A + (size_t)(tm + rl) * CD + sp * 8, (char*)Al[0] + w * 1024 + i * 4096);
    GLOAD16(Bt + (size_t)(tn + rl) * CD + sp * 8, (char*)Bl[0] + w * 1024 + i * 4096);
  }
  __syncthreads();

  int cur = 0;
  for (int kt = 0; kt < 8; ++kt) {
    if (kt + 1 < 8) {
      int nxt = cur ^ 1;
#pragma unroll
      for (int i = 0; i < 4; i++) {
        int rl = rowA + 32 * i;
        int sp = sl ^ (rl & 7);
        GLOAD16(A + (size_t)(tm + rl) * CD + (kt + 1) * 64 + sp * 8,
                (char*)Al[nxt] + w * 1024 + i * 4096);
        GLOAD16(Bt + (size_t)(tn + rl) * CD + (kt + 1) * 64 + sp * 8,
                (char*)Bl[nxt] + w * 1024 + i * 4096);
      }
    }
    const u16* Ac = Al[cur];
    const u16* Bc = Bl[cur];
#pragma unroll
    for (int kk = 0; kk < 2; kk++) {
      bf16x8 af[4], bfr[4];
#pragma unroll
      for (int mi = 0; mi < 4; mi++) {
        int row = wr * 64 + mi * 16 + (l & 15);
        int slot = ((l >> 4) + 4 * kk) ^ (row & 7);
        af[mi] = *(const bf16x8*)&Ac[row * 64 + slot * 8];
      }
#pragma unroll
      for (int ni = 0; ni < 4; ni++) {
        int row = wc * 64 + ni * 16 + (l & 15);
        int slot = ((l >> 4) + 4 * kk) ^ (row & 7);
        bfr[ni] = *(const bf16x8*)&Bc[row * 64 + slot * 8];
      }
#pragma unroll
      for (int mi = 0; mi < 4; mi++)
#pragma unroll
        for (int ni = 0; ni < 4; ni++)
          acc[mi][ni] = MFMA(af[mi], bfr[ni], acc[mi][ni]);
    }
    if (kt + 1 < 8) {
      __syncthreads();
      cur ^= 1;
    }
  }
#pragma unroll
  for (int mi = 0; mi < 4; mi++)
#pragma unroll
    for (int ni = 0; ni < 4; ni++) {
      int col = tn + wc * 64 + ni * 16 + (l & 15);
      float bv = ADD_BIAS ? bias[col] : 0.f;
#pragma unroll
      for (int rg = 0; rg < 4; rg++) {
        int rowg = tm + wr * 64 + mi * 16 + (l >> 4) * 4 + rg;
        float vout = acc[mi][ni][rg] + bv;
        if (OUT_BF16)
          ((u16*)Cout)[(size_t)rowg * CD + col] = f2bf(vout);
        else
          ((float*)Cout)[(size_t)rowg * CD + col] = vout;
      }
    }
}

// ---------------------------------------------------------------------------
// K1b: transpose fv + rank-1 partial
// ---------------------------------------------------------------------------
__global__ __launch_bounds__(256) void transpose_v(const u16* __restrict__ F2,
                                                   const float* __restrict__ mk,
                                                   u16* __restrict__ fvT,
                                                   float* __restrict__ rpart) {
  int bid = blockIdx.x;
  int nt = bid & 31, b = (bid >> 5) & 1, h = bid >> 6;
  __shared__ u16 T[64 * 72];
  int tid = threadIdx.x;
  int n = tid >> 2;
#pragma unroll
  for (int p = 0; p < 2; p++) {
    int c = (tid & 3) + 4 * p;
    bf16x8 vv = *(const bf16x8*)&F2[((size_t)(b * CN + nt * 64 + n) * CD) + h * 64 + c * 8];
    *(bf16x8*)&T[n * 72 + c * 8] = vv;
  }
  __syncthreads();
  int d = tid >> 2;
#pragma unroll
  for (int p = 0; p < 2; p++) {
    int c = (tid & 3) + 4 * p;
    u16 tmp[8];
#pragma unroll
    for (int j = 0; j < 8; j++) tmp[j] = T[(c * 8 + j) * 72 + d];
    *(bf16x8*)&fvT[(((size_t)(h * 2 + b) * 64 + d) * CN) + nt * 64 + c * 8] =
        *(bf16x8*)tmp;
  }
  {
    int d2 = tid & 63, sub = tid >> 6;
    const float* mkp = mk + ((size_t)(h * 2 + b)) * CN + nt * 64;
    float s = 0.f;
#pragma unroll
    for (int i = 0; i < 16; i++) {
      int n2 = sub * 16 + i;
      s += mkp[n2] * bf2f(T[n2 * 72 + d2]);
    }
    __shared__ float rred[4][64];
    rred[sub][d2] = s;
    __syncthreads();
    if (sub == 0)
      rpart[(((size_t)(h * 2 + b)) * 32 + nt) * 64 + d2] =
          rred[0][d2] + rred[1][d2] + rred[2][d2] + rred[3][d2];
  }
}

// ---------------------------------------------------------------------------
// K1c: per-(h,b,n) stats
// ---------------------------------------------------------------------------
__global__ __launch_bounds__(256) void stats_kernel(const u16* __restrict__ F,
                                                    float* __restrict__ iqn,
                                                    float* __restrict__ mq,
                                                    float* __restrict__ ikn,
                                                    float* __restrict__ mk) {
  unsigned idx = blockIdx.x * 256 + threadIdx.x;
  int h = idx & 7;
  int n = (idx >> 3) & 2047;
  int b = (idx >> 14) & 1;
  int t = idx >> 15;
  const u16* p = F + ((size_t)(t * 4096 + b * CN + n)) * CD + h * 64;
  float s1 = 0.f, s2 = 0.f;
  const uint4* p4 = (const uint4*)p;
#pragma unroll
  for (int j = 0; j < 8; j++) {
    uint4 u = p4[j];
    unsigned arr[4] = {u.x, u.y, u.z, u.w};
#pragma unroll
    for (int e = 0; e < 4; e++) {
      float lo = bf2f((u16)(arr[e] & 0xFFFF));
      float hi = bf2f((u16)(arr[e] >> 16));
      s1 += lo + hi;
      s2 += lo * lo + hi * hi;
    }
  }
  float inv = 1.f / sqrtf(s2);
  float mean = s1 * (1.f / 64.f);
  size_t o = ((size_t)h * 2 + b) * CN + n;
  if (t == 0) { iqn[o] = inv; mq[o] = mean; }
  else        { ikn[o] = inv; mk[o] = mean; }
}

// ---------------------------------------------------------------------------
// K2a: partial sums of fq,fk over rows -> qgp/kgp [32ch][8h][64]
// ---------------------------------------------------------------------------
__global__ __launch_bounds__(256) void gsum_kernel(const u16* __restrict__ F0,
                                                   const u16* __restrict__ F1,
                                                   float* __restrict__ qgp,
                                                   float* __restrict__ kgp) {
  int h = blockIdx.x & 7, ch = blockIdx.x >> 3;
  int tid = threadIdx.x;
  int r0 = tid >> 3;
  int dc = (tid & 7) * 8;
  float aq[8], ak[8];
#pragma unroll
  for (int j = 0; j < 8; j++) { aq[j] = 0.f; ak[j] = 0.f; }
#pragma unroll
  for (int i = 0; i < 4; i++) {
    int row = ch * 128 + i * 32 + r0;
    bf16x8 vq = *(const bf16x8*)&F0[(size_t)row * CD + h * 64 + dc];
    bf16x8 vk = *(const bf16x8*)&F1[(size_t)row * CD + h * 64 + dc];
#pragma unroll
    for (int j = 0; j < 8; j++) { aq[j] += (float)vq[j]; ak[j] += (float)vk[j]; }
  }
  __shared__ float red[2][32][64];
#pragma unroll
  for (int j = 0; j < 8; j++) { red[0][r0][dc + j] = aq[j]; red[1][r0][dc + j] = ak[j]; }
  __syncthreads();
  if (tid < 64) {
    float sq = 0.f, sk = 0.f;
#pragma unroll
    for (int rr = 0; rr < 32; rr++) { sq += red[0][rr][tid]; sk += red[1][rr][tid]; }
    qgp[(ch * 8 + h) * 64 + tid] = sq;
    kgp[(ch * 8 + h) * 64 + tid] = sk;
  }
}

// ---------------------------------------------------------------------------
// K2f: finalize reductions + per-head blend MLP (merged), 1 block x 1024 thr
// ---------------------------------------------------------------------------
__global__ __launch_bounds__(1024) void finalize_mlp_kernel(
    const float* __restrict__ rpart, const float* __restrict__ qgp,
    const float* __restrict__ kgp, const float* __restrict__ w1,
    const float* __restrict__ b1, const float* __restrict__ lng,
    const float* __restrict__ lnb, const float* __restrict__ w2,
    const float* __restrict__ b2, float* __restrict__ rv,
    float* __restrict__ hp) {
  int o = threadIdx.x;
  int hb = o >> 6, d = o & 63;
  float s = 0.f;
#pragma unroll
  for (int nt = 0; nt < 32; nt++) s += rpart[((size_t)hb * 32 + nt) * 64 + d];
  rv[o] = s;
  __shared__ float qg[512], kg[512];
  if (o < 512) {
    int h = o >> 6, dd = o & 63;
    float s1 = 0.f, s2 = 0.f;
#pragma unroll
    for (int c = 0; c < 32; c++) {
      s1 += qgp[(c * 8 + h) * 64 + dd];
      s2 += kgp[(c * 8 + h) * 64 + dd];
    }
    qg[o] = s1 * (1.f / 4096.f);
    kg[o] = s2 * (1.f / 4096.f);
  }
  __syncthreads();
  if (o < 512) {
    int h = o >> 6, oo = o & 63;
    float acc = b1[oo];
#pragma unroll 8
    for (int i = 0; i < 64; i++)
      acc += qg[h * 64 + i] * w1[oo * 128 + i] + kg[h * 64 + i] * w1[oo * 128 + 64 + i];
    float s1 = acc, s2 = acc * acc;
#pragma unroll
    for (int m = 1; m < 64; m <<= 1) { s1 += __shfl_xor(s1, m); s2 += __shfl_xor(s2, m); }
    float mean = s1 * (1.f / 64.f);
    float var = s2 * (1.f / 64.f) - mean * mean;
    float y = (acc - mean) * rsqrtf(var + 1e-5f) * lng[oo] + lnb[oo];
    float hid = fmaxf(y, 0.f);
    float t = hid * w2[oo];
#pragma unroll
    for (int m = 1; m < 64; m <<= 1) t += __shfl_xor(t, m);
    float wv = 1.f / (1.f + expf(-(t + b2[0])));
    if (oo == 0) {
      hp[h * 4 + 0] = 1.f - wv;
      hp[h * 4 + 1] = wv * (1.f / 64.f);
      hp[h * 4 + 2] = wv;
    }
  }
}

// ---------------------------------------------------------------------------
// K3: streaming blended attention. R3 pipeline (STAGE->QKP->PV->barrier, K+V
// in LDS dbuf) + XCD-bijective swizzle (K/V panels L2-resident) + ik prefetch.
// grid 512, 256 threads (4 waves). 1 barrier/iter; P tile wave-private.
// ---------------------------------------------------------------------------
__global__ __launch_bounds__(256) void attn_kernel(const u16* __restrict__ F0,
                                                   const u16* __restrict__ F1,
                                                   const u16* __restrict__ fvT,
                                                   const float* __restrict__ iqn,
                                                   const float* __restrict__ mq_g,
                                                   const float* __restrict__ ikn,
                                                   const float* __restrict__ hp,
                                                   const float* __restrict__ rv,
                                                   u16* __restrict__ A2) {
  // XCD swizzle (bijective, 512 = 8*64): each XCD owns 2 full (h,b) panels.
  int bid = (blockIdx.x & 7) * 64 + (blockIdx.x >> 3);
  int qt = bid & 31, b = (bid >> 5) & 1, h = bid >> 6;
  int tid = threadIdx.x, w = tid >> 6, l = tid & 63;
  float alpha = hp[h * 4 + 0], beta = hp[h * 4 + 1], gamma = hp[h * 4 + 2];

  __shared__ u16 Kl[2][64 * 64];   // K tiles (rows m, swizzled slots)
  __shared__ u16 Vl[2][64 * 64];   // V^T tiles (rows d, swizzled slots)
  __shared__ u16 Pl[64 * 72];      // P tile (wave-private rows)

  int qbase = qt * 64;
  int nloc = w * 16 + (l & 15);
  const u16* qp = F0 + ((size_t)(b * CN + qbase + nloc)) * CD + h * 64 + (l >> 4) * 8;
  bf16x8 aq0 = *(const bf16x8*)qp;
  bf16x8 aq1 = *(const bf16x8*)(qp + 32);

  const float* iqn_hb = iqn + ((size_t)h * 2 + b) * CN;
  const float* mq_hb = mq_g + ((size_t)h * 2 + b) * CN;
  const float* ikn_hb = ikn + ((size_t)h * 2 + b) * CN;
  float aqn[4], mqg[4];
#pragma unroll
  for (int rg = 0; rg < 4; rg++) {
    int nr = qbase + w * 16 + (l >> 4) * 4 + rg;
    aqn[rg] = alpha * iqn_hb[nr];
    mqg[rg] = gamma * mq_hb[nr];
  }

  f32x4 zz = {0.f, 0.f, 0.f, 0.f};
  f32x4 oacc[4];
#pragma unroll
  for (int db = 0; db < 4; db++) oacc[db] = zz;

  const u16* Kg = F1 + (size_t)b * CN * CD + h * 64;
  const u16* Vg = fvT + ((size_t)h * 2 + b) * 64 * CN;

  int rls = 8 * w + (l >> 3);
  int sls = l & 7;

  float ikA[4], ikB[4];   // per-tile inv-k-norm prefetch (one tile ahead)

  auto STAGE = [&](int t, int slot) {
    int mb2 = t * 64;
#pragma unroll
    for (int i = 0; i < 2; i++) {
      int row = rls + 32 * i;
      int sp = sls ^ (row & 7);
      GLOAD16(Kg + (size_t)(mb2 + row) * CD + sp * 8,
              (char*)Kl[slot] + w * 1024 + i * 4096);
      GLOAD16(Vg + (size_t)row * CN + mb2 + sp * 8,
              (char*)Vl[slot] + w * 1024 + i * 4096);
    }
  };
  auto LOADIK = [&](float (&ik)[4], int t) {
    int mbase = t * 64;
#pragma unroll
    for (int mb = 0; mb < 4; mb++) ik[mb] = ikn_hb[mbase + mb * 16 + (l & 15)];
  };
  auto QKP = [&](const u16* Kc, const float (&ik)[4]) {
#pragma unroll
    for (int mb = 0; mb < 4; mb++) {
      int rowk = mb * 16 + (l & 15);
      int c0 = (l >> 4) ^ (rowk & 7);
      int c1 = ((l >> 4) + 4) ^ (rowk & 7);
      bf16x8 bk0 = *(const bf16x8*)&Kc[rowk * 64 + c0 * 8];
      bf16x8 bk1 = *(const bf16x8*)&Kc[rowk * 64 + c1 * 8];
      f32x4 dacc = zz;
      dacc = MFMA(aq0, bk0, dacc);
      dacc = MFMA(aq1, bk1, dacc);
#pragma unroll
      for (int rg = 0; rg < 4; rg++) {
        float pv = dacc[rg] * (aqn[rg] * ik[mb] + beta);
        Pl[(w * 16 + (l >> 4) * 4 + rg) * 72 + mb * 16 + (l & 15)] = f2bf_hw(pv);
      }
    }
  };
  auto PV = [&](const u16* Vc) {
#pragma unroll
    for (int c = 0; c < 2; c++) {
      bf16x8 ap = *(const bf16x8*)&Pl[(w * 16 + (l & 15)) * 72 + (l >> 4) * 8 + c * 32];
#pragma unroll
      for (int db = 0; db < 4; db++) {
        int rowd = db * 16 + (l & 15);
        int ck = ((l >> 4) + 4 * c) ^ (rowd & 7);
        bf16x8 bv = *(const bf16x8*)&Vc[rowd * 64 + ck * 8];
        oacc[db] = MFMA(ap, bv, oacc[db]);
      }
    }
  };

  // prologue: tile 0 into buf 0
  STAGE(0, 0);
  LOADIK(ikA, 0);
  __syncthreads();   // implicit vmcnt(0): tile 0 resident

  for (int t = 0; t < 32; t += 2) {
    // even tile t (buf 0): first issue next tile's loads, then compute
    STAGE(t + 1, 1);          // t+1 <= 31 always (t <= 30)
    LOADIK(ikB, t + 1);
    QKP(Kl[0], ikA);
    PV(Vl[0]);
    __syncthreads();          // tile t+1 resident; all waves done with buf 0

    // odd tile t+1 (buf 1)
    if (t + 2 < 32) {
      STAGE(t + 2, 0);
      LOADIK(ikA, t + 2);
    }
    QKP(Kl[1], ikB);
    PV(Vl[1]);
    __syncthreads();
  }

  // epilogue: rank-1 covariance correction + bf16 store
  const float* r_hb = rv + ((size_t)h * 2 + b) * 64;
#pragma unroll
  for (int db = 0; db < 4; db++) {
    int dcol = db * 16 + (l & 15);
    float rd = r_hb[dcol];
#pragma unroll
    for (int rg = 0; rg < 4; rg++) {
      int nr = qbase + w * 16 + (l >> 4) * 4 + rg;
      float v = oacc[db][rg] - mqg[rg] * rd;
      A2[((size_t)(b * CN + nr)) * CD + h * 64 + dcol] = f2bf(v);
    }
  }
}

// ---------------------------------------------------------------------------
extern "C" void kernel_launch(void* const* d_in, const int* in_sizes, int n_in,
                              void* d_out, int out_size, void* d_ws, size_t ws_size,
                              hipStream_t stream) {
  const float* q = (const float*)d_in[0];
  const float* k = (const float*)d_in[1];
  const float* v = (const float*)d_in[2];
  const float* ln_g = (const float*)d_in[3];
  const float* ln_b = (const float*)d_in[4];
  const float* W_in = (const float*)d_in[5];
  const float* wp_w1 = (const float*)d_in[6];
  const float* wp_b1 = (const float*)d_in[7];
  const float* wp_lng = (const float*)d_in[8];
  const float* wp_lnb = (const float*)d_in[9];
  const float* wp_w2 = (const float*)d_in[10];
  const float* wp_b2 = (const float*)d_in[11];
  const float* W_out = (const float*)d_in[12];
  const float* b_out = (const float*)d_in[13];

  char* ws = (char*)d_ws;
  u16* xln = (u16*)(ws + 0);              // 12,582,912 B
  u16* F = (u16*)(ws + 12582912);         // 12,582,912 B  [3][B][N][512]
  u16* Wi = (u16*)(ws + 25165824);        // 524,288 B
  u16* Wo = (u16*)(ws + 25690112);        // 524,288 B
  u16* fvT = (u16*)(ws + 26214400);       // 4,194,304 B   [H][B][64][2048]
  u16* A2 = (u16*)(ws + 30408704);        // 4,194,304 B   [B][N][512]
  float* iqn = (float*)(ws + 34603008);   // 131,072 B each
  float* mq = (float*)(ws + 34734080);
  float* ikn = (float*)(ws + 34865152);
  float* mk = (float*)(ws + 34996224);
  float* qgp = (float*)(ws + 35127296);   // 65,536 B
  float* kgp = (float*)(ws + 35192832);   // 65,536 B
  float* hp = (float*)(ws + 35258368);    // 128 B
  float* rv = (float*)(ws + 35258496);    // 4,096 B
  float* rpart = (float*)(ws + 35262592); // 131,072 B

  u16* F0 = F;
  u16* F1 = F + 2097152;
  u16* F2 = F + 4194304;

  ln_kernel<<<12288, 256, 0, stream>>>(q, k, v, ln_g, ln_b, xln);
  convw_kernel<<<1024, 256, 0, stream>>>(W_in, W_out, Wi, Wo);
  gemm_bt<1, 0><<<dim3(96, 4), 256, 0, stream>>>(xln, Wi, (void*)F, nullptr);
  stats_kernel<<<256, 256, 0, stream>>>(F, iqn, mq, ikn, mk);
  transpose_v<<<512, 256, 0, stream>>>(F2, mk, fvT, rpart);
  gsum_kernel<<<256, 256, 0, stream>>>(F0, F1, qgp, kgp);
  finalize_mlp_kernel<<<1, 1024, 0, stream>>>(rpart, qgp, kgp, wp_w1, wp_b1,
                                              wp_lng, wp_lnb, wp_w2, wp_b2, rv, hp);
  attn_kernel<<<512, 256, 0, stream>>>(F0, F1, fvT, iqn, mq, ikn, hp, rv, A2);
  gemm_bt<0, 1><<<dim3(32, 4), 256, 0, stream>>>(A2, Wo, d_out, b_out);
}